// Round 9
// baseline (24.666 us; speedup 1.0000x reference)
//
#include <hip/hip_runtime.h>
#include <math.h>

// Problem constants (setup_inputs: L=8, B=2, N=2048)
constexpr int L = 8;
constexpr int B = 2;
constexpr int N = 2048;
constexpr int LB = L * B;            // 16
constexpr int KF = 32;               // padded feature dim (28 used + residual)

constexpr float D_CLAMP2 = 100.0f;   // clamp on squared distance
constexpr float FAPE_EPS = 1e-4f;
constexpr float Z_CONST  = 10.0f;
constexpr float TEPS     = 1e-8f;

constexpr int THREADS = 512;                 // 8 waves
constexpr int IBLK    = 256;                 // i rows per block
constexpr int JCH     = 512;                 // j cols per block
constexpr int NIT     = N / IBLK;            // 8 i-tiles per (l,b)
constexpr int JSPLIT  = N / JCH;             // 4 j-chunks per (l,b)
constexpr int BLK_PER_LB  = NIT * JSPLIT;    // 32
constexpr int FAPE_BLOCKS = LB * BLK_PER_LB; // 512 (2 per CU, 16 waves/CU)
constexpr int TORS_PER_BLK = N / BLK_PER_LB; // 64 torsion items per block

// fixed-point scale for deterministic i64 accumulation (order-invariant)
constexpr double ACC_SCALE  = 36028797018963968.0;   // 2^55
constexpr double ACC_ISCALE = 1.0 / 36028797018963968.0;

typedef __attribute__((ext_vector_type(8))) short bf16x8;
typedef __attribute__((ext_vector_type(4))) float f32x4;

__device__ __forceinline__ float fast_sqrtf(float x) {
    return __builtin_amdgcn_sqrtf(x);
}
// HW packed f32->bf16 (RNE on gfx950); 1 instr per 2 values
__device__ __forceinline__ unsigned cvt_pk(float lo, float hi) {
    unsigned r;
    asm("v_cvt_pk_bf16_f32 %0, %1, %2" : "=v"(r) : "v"(lo), "v"(hi));
    return r;
}
__device__ __forceinline__ float bf2f(unsigned short h) {
    return __uint_as_float((unsigned)h << 16);
}

__device__ __forceinline__ float wave_reduce_sum(float v) {
    #pragma unroll
    for (int off = 32; off > 0; off >>= 1)
        v += __shfl_down(v, off, 64);
    return v;            // valid in lane 0
}

__device__ __forceinline__ float block_reduce_sum(float v) {
    __shared__ float s[8];
    v = wave_reduce_sum(v);
    int lane = threadIdx.x & 63;
    int w    = threadIdx.x >> 6;
    __syncthreads();
    if (lane == 0) s[w] = v;
    __syncthreads();
    float r = 0.f;
    #pragma unroll
    for (int k = 0; k < 8; ++k) r += s[k];   // fixed order -> deterministic
    return r;
}

// LDS chunk swizzle: 16B chunk c of row r stored at position c ^ ((r>>1)&3).
// Write (64 lanes x 4 chunks) and MFMA-fragment read (16 rows x 4 k-chunks)
// both hit each bank exactly twice per wave access = structural minimum
// (verified 0 SQ_LDS_BANK_CONFLICT in rounds 7/8).
__device__ __forceinline__ void store_row(short* base, int r, const float* f) {
    #pragma unroll
    for (int c = 0; c < 4; ++c) {
        union { unsigned u[4]; bf16x8 v; } q;
        #pragma unroll
        for (int e = 0; e < 4; ++e)
            q.u[e] = cvt_pk(f[8 * c + 2 * e], f[8 * c + 2 * e + 1]);
        const int p = c ^ ((r >> 1) & 3);
        *(bf16x8*)(base + r * KF + p * 8) = q.v;
    }
}
__device__ __forceinline__ bf16x8 load_frag(const short* base, int r, int c) {
    const int p = c ^ ((r >> 1) & 3);
    return *(const bf16x8*)(base + r * KF + p * 8);
}

// ---------------------------------------------------------------------------
// Self-sufficient FAPE block: 256 i x 512 j, 8 waves. Computes its psi
// (256 rows) and phi (512 rows) features into LDS, its torsion slice
// (64 items), then the MFMA pair loop. Block result is accumulated into a
// per-b i64 fixed-point accumulator (deterministic, order-invariant).
// Factorization: ||W u_j + k||^2 + eps = psi(i) . phi(j), W=[Rp^T|-Rt^T],
// k = -W u_i.  psi: [0..5]=Q_cc, [6..20]=2Q_cd, [21..26]=2(W^T k)_c,
// [27]=|k|^2+eps, [28]=bf16 residual of [27]; phi: [u_c^2, u_c u_d, u_c, 1, 1].
// ---------------------------------------------------------------------------
__global__ __launch_bounds__(THREADS, 4)
void fape_all_kernel(const float* __restrict__ traj_rot,    // [L,B,N,3,3]
                     const float* __restrict__ traj_trans,  // [L,B,N,3]
                     const float* __restrict__ traj_tors,   // [L,B,N,7,2]
                     const float* __restrict__ true_rot,    // [B,N,3,3]
                     const float* __restrict__ true_trans,  // [B,N,3]
                     const float* __restrict__ t_true,      // [B,N,7,2]
                     const float* __restrict__ t_alt,       // [B,N,7,2]
                     unsigned long long* __restrict__ acc64) // [B]
{
    __shared__ short phiL[JCH * KF];    // 32 KB
    __shared__ short psiL[IBLK * KF];   // 16 KB
    __shared__ float tors_s;

    const int bid = blockIdx.x;
    const int jh  = bid & (JSPLIT - 1);
    const int it  = (bid >> 2) & (NIT - 1);
    const int lb  = bid >> 5;            // 32 blocks per lb
    const int b   = lb & (B - 1);
    const int tid = threadIdx.x;

    const float* tp = traj_trans + (size_t)lb * N * 3;
    const float* tt = true_trans + (size_t)b  * N * 3;

    // ---- phi prep: one row per thread ----
    {
        const int r = tid;                       // 0..511
        const int j = jh * JCH + r;
        float u[6] = { tp[3 * j], tp[3 * j + 1], tp[3 * j + 2],
                       tt[3 * j], tt[3 * j + 1], tt[3 * j + 2] };
        float phi[KF];
        #pragma unroll
        for (int c = 0; c < 6; ++c) phi[c] = u[c] * u[c];
        int idx = 6;
        #pragma unroll
        for (int c = 0; c < 6; ++c)
            #pragma unroll
            for (int d = c + 1; d < 6; ++d)
                phi[idx++] = u[c] * u[d];
        #pragma unroll
        for (int c = 0; c < 6; ++c) phi[21 + c] = u[c];
        phi[27] = 1.0f;
        phi[28] = 1.0f;
        phi[29] = phi[30] = phi[31] = 0.0f;
        store_row(phiL, r, phi);
    }

    // ---- psi prep: threads 0..255, one i-row each ----
    if (tid < IBLK) {
        const int r = tid;
        const int i = it * IBLK + r;
        const float* Rp = traj_rot + ((size_t)lb * N + i) * 9;
        const float* Rt = true_rot + ((size_t)(b * N + i)) * 9;

        float W0[6], W1[6], W2[6];
        #pragma unroll
        for (int c = 0; c < 3; ++c) {
            W0[c] = Rp[3 * c];      W1[c] = Rp[3 * c + 1];      W2[c] = Rp[3 * c + 2];
            W0[c + 3] = -Rt[3 * c]; W1[c + 3] = -Rt[3 * c + 1]; W2[c + 3] = -Rt[3 * c + 2];
        }
        float u[6] = { tp[3 * i], tp[3 * i + 1], tp[3 * i + 2],
                       tt[3 * i], tt[3 * i + 1], tt[3 * i + 2] };

        float k0 = 0.f, k1 = 0.f, k2 = 0.f;
        #pragma unroll
        for (int c = 0; c < 6; ++c) {
            k0 = fmaf(W0[c], u[c], k0);
            k1 = fmaf(W1[c], u[c], k1);
            k2 = fmaf(W2[c], u[c], k2);
        }
        k0 = -k0; k1 = -k1; k2 = -k2;

        float psi[KF];
        #pragma unroll
        for (int c = 0; c < 6; ++c)
            psi[c] = fmaf(W0[c], W0[c], fmaf(W1[c], W1[c], W2[c] * W2[c]));
        int idx = 6;
        #pragma unroll
        for (int c = 0; c < 6; ++c)
            #pragma unroll
            for (int d = c + 1; d < 6; ++d)
                psi[idx++] = 2.0f * fmaf(W0[c], W0[d], fmaf(W1[c], W1[d], W2[c] * W2[d]));
        #pragma unroll
        for (int c = 0; c < 6; ++c)
            psi[21 + c] = 2.0f * fmaf(W0[c], k0, fmaf(W1[c], k1, W2[c] * k2));
        psi[27] = fmaf(k0, k0, fmaf(k1, k1, fmaf(k2, k2, FAPE_EPS)));
        // residual vs the SAME hw conversion the store uses -> self-consistent
        psi[28] = psi[27] - bf2f((unsigned short)(cvt_pk(psi[27], psi[27]) & 0xffffu));
        psi[29] = psi[30] = psi[31] = 0.0f;
        store_row(psiL, r, psi);
    }

    // ---- torsion: wave 7, one item per lane (64 items per block) ----
    if (tid >= 448) {
        const int t  = tid - 448;
        const int n  = (bid & 31) * TORS_PER_BLK + t;
        const int g  = lb * N + n;
        const int bn = b * N + n;
        const float* p  = traj_tors + (size_t)g * 14;
        const float* tr = t_true + (size_t)bn * 14;
        const float* al = t_alt  + (size_t)bn * 14;

        float st = 0.0f, sa = 0.0f;
        #pragma unroll
        for (int k = 0; k < 7; ++k) {
            const float px = p[2 * k], py = p[2 * k + 1];
            const float nrm = fast_sqrtf(fmaf(px, px, fmaf(py, py, TEPS)));
            const float inv = __builtin_amdgcn_rcpf(nrm);
            const float pnx = px * inv, pny = py * inv;
            const float tx = tr[2 * k] - pnx, ty = tr[2 * k + 1] - pny;
            const float ax = al[2 * k] - pnx, ay = al[2 * k + 1] - pny;
            const float dt = fast_sqrtf(fmaf(tx, tx, fmaf(ty, ty, TEPS)));
            const float da = fast_sqrtf(fmaf(ax, ax, fmaf(ay, ay, TEPS)));
            st += fminf(dt, da);
            sa += fabsf(nrm - 1.0f);
        }
        float val = (st + 0.02f * sa) * (1.0f / 7.0f);
        val = wave_reduce_sum(val);
        if (tid == 448) tors_s = val;
    }

    __syncthreads();

    // ---- MFMA pair loop: 8 waves, each 128 i x 128 j ----
    const int w    = tid >> 6;
    const int lane = tid & 63;
    const int wm   = w >> 2;             // i half (128 rows)
    const int wn   = w & 3;              // j quarter (128 cols)
    const int r15  = lane & 15;
    const int cch  = lane >> 4;          // k-chunk 0..3

    bf16x8 a[8];                         // 8 A-frags in registers (32 VGPR)
    #pragma unroll
    for (int s = 0; s < 8; ++s)
        a[s] = load_frag(psiL, wm * 128 + s * 16 + r15, cch);

    const f32x4 z = { 0.f, 0.f, 0.f, 0.f };
    float acc0 = 0.f, acc1 = 0.f, acc2 = 0.f, acc3 = 0.f;

    #pragma unroll
    for (int q = 0; q < 8; ++q) {        // 8 B-frags
        const bf16x8 bq = load_frag(phiL, wn * 128 + q * 16 + r15, cch);
        f32x4 d[8];
        #pragma unroll
        for (int s = 0; s < 8; ++s)
            d[s] = __builtin_amdgcn_mfma_f32_16x16x32_bf16(a[s], bq, z, 0, 0, 0);
        #pragma unroll
        for (int s = 0; s < 8; ++s) {
            acc0 += fast_sqrtf(__builtin_amdgcn_fmed3f(d[s][0], 0.f, D_CLAMP2));
            acc1 += fast_sqrtf(__builtin_amdgcn_fmed3f(d[s][1], 0.f, D_CLAMP2));
            acc2 += fast_sqrtf(__builtin_amdgcn_fmed3f(d[s][2], 0.f, D_CLAMP2));
            acc3 += fast_sqrtf(__builtin_amdgcn_fmed3f(d[s][3], 0.f, D_CLAMP2));
        }
    }

    const float tot = block_reduce_sum((acc0 + acc1) + (acc2 + acc3));
    if (tid == 0) {
        // partial already carries all scaling: /(N*N*Z*L) and /(N*L)
        const float partial = tot * (1.0f / ((float)N * (float)N * Z_CONST * (float)L))
                            + tors_s * (1.0f / ((float)N * (float)L));
        const unsigned long long q =
            (unsigned long long)(long long)((double)partial * ACC_SCALE + 0.5);
        atomicAdd(&acc64[b], q);   // integer add: order-invariant, deterministic
    }
}

// ---------------------------------------------------------------------------
// Finalize: out[b] = acc64[b] * 2^-55   (single tiny dispatch)
// ---------------------------------------------------------------------------
__global__ void finalize_kernel(const unsigned long long* __restrict__ acc64,
                                float* __restrict__ out)
{
    if (threadIdx.x < B)
        out[threadIdx.x] = (float)((double)acc64[threadIdx.x] * ACC_ISCALE);
}

extern "C" void kernel_launch(void* const* d_in, const int* in_sizes, int n_in,
                              void* d_out, int out_size, void* d_ws, size_t ws_size,
                              hipStream_t stream)
{
    const float* traj_rot   = (const float*)d_in[0];
    const float* traj_trans = (const float*)d_in[1];
    const float* traj_tors  = (const float*)d_in[2];
    const float* true_rot   = (const float*)d_in[3];
    const float* true_trans = (const float*)d_in[4];
    const float* true_ta    = (const float*)d_in[5];
    const float* true_taa   = (const float*)d_in[6];

    float* out = (float*)d_out;
    unsigned long long* acc64 = (unsigned long long*)d_ws;   // [B]

    hipMemsetAsync(acc64, 0, B * sizeof(unsigned long long), stream);

    fape_all_kernel<<<FAPE_BLOCKS, THREADS, 0, stream>>>(
        traj_rot, traj_trans, traj_tors, true_rot, true_trans,
        true_ta, true_taa, acc64);
    finalize_kernel<<<1, 64, 0, stream>>>(acc64, out);
}